// Round 11
// baseline (253.337 us; speedup 1.0000x reference)
//
#include <hip/hip_runtime.h>
#include <math.h>

#define NMEL   40
#define NCEP   13
#define BATCH  1024
#define NSAMP  16000
#define NFRAME 49
#define PI_F   3.14159265358979323846f

// d_ws float layout
#define WS_WIN  0        // 640 floats: Hann window
#define WS_R    640      // 512 float2: W_1024^k, k=0..511 (1024 floats)
#define WS_DT   1664     // 520 floats: DCT * 1/sqrt(80) * lifter, [40][13]
#define WS_BT   2184     // f16 area: Bt[48][544] mel weights transposed (13056 floats)
#define WS_TOT  15240

typedef _Float16 half8 __attribute__((ext_vector_type(8)));
typedef __fp16   fp16x2 __attribute__((ext_vector_type(2)));
typedef float f32x4 __attribute__((ext_vector_type(4)));

// Compiler-only ordering fence (DS ops of one wave execute in order).
#define WAVE_FENCE() { __builtin_amdgcn_wave_barrier(); asm volatile("" ::: "memory"); }

// radix-2 DIF butterfly on register arrays
#define BFLY(i0, i1, wr, wi) {                        \
    float tr = zr[i0] - zr[i1], ti = zi[i0] - zi[i1]; \
    zr[i0] += zr[i1]; zi[i0] += zi[i1];               \
    zr[i1] = tr*(wr) - ti*(wi);                       \
    zi[i1] = tr*(wi) + ti*(wr); }

__device__ __forceinline__ unsigned pk_f16(float a, float b) {
    fp16x2 h = __builtin_amdgcn_cvt_pkrtz(a, b);
    union { fp16x2 h; unsigned u; } cvt; cvt.h = h;
    return cvt.u;
}

// ---------------------------------------------------------------------------
// Prep: window / twiddle / DCT tables + transposed, padded f16 mel weights.
// ---------------------------------------------------------------------------
__global__ __launch_bounds__(256) void mfcc_prep(
    const float* __restrict__ mel_fb, float* __restrict__ ws)
{
    const int idx = blockIdx.x * 256 + threadIdx.x;   // grid = 64 blocks

    _Float16* bt = (_Float16*)(ws + WS_BT);
    for (int i = idx; i < 48 * 544; i += 64 * 256) {
        int n = i / 544, k = i - n * 544;
        float v = (n < NMEL && k < 513) ? mel_fb[k * NMEL + n] : 0.0f;
        bt[i] = (_Float16)v;
    }

    if (idx < 640 + 512 + 520) {
        int i = idx;
        if (i < 640) {
            ws[WS_WIN + i] = 0.5f - 0.5f * cosf(2.0f * PI_F * (float)i / 640.0f);
        } else if (i < 1152) {
            int k = i - 640;
            float s, c;
            sincosf(-2.0f * PI_F * (float)k / 1024.0f, &s, &c);
            ((float2*)(ws + WS_R))[k] = make_float2(c, s);
        } else {
            int j = i - 1152;
            int m = j / 13, c0 = j - m * 13;
            float d    = 2.0f * cosf(PI_F * (2.0f * m + 1.0f) * (float)c0 / 80.0f);
            float lift = 1.0f + 11.0f * sinf(PI_F * (float)c0 / 22.0f);
            ws[WS_DT + j] = d * 0.11180339887498949f * lift;   // 1/sqrt(80)
        }
    }
}

// ---------------------------------------------------------------------------
// Fused kernel: one block = one batch (grid 1024). 4 chunks of <=16 frames:
// FFT (r10 structure, wave-private padded Z, slot(x)=x+2(x>>3)) -> mag f16
// overlay on dead Z -> mel MFMA -> DCT -> cep in LDS. Then in-block deltas,
// single write of all 39 channels. Kills the separate stage2 kernel + its
// launch gap + the out round-trip (r10 post-mortem: constant ~73us non-FFT
// overhead across 6 rounds).
// ---------------------------------------------------------------------------
__global__ __launch_bounds__(256) void mfcc_fused(
    const float* __restrict__ wave, const float* __restrict__ ws,
    float* __restrict__ out)
{
    __shared__ __align__(16) char smem[4 * 640 * 8];   // Z[4][640] / mag[16][552]
    __shared__ _Float16 lm[NFRAME * NMEL];             // log-mel, f32->f16
    __shared__ float cep[NFRAME * NCEP];
    __shared__ float d1b[NFRAME * NCEP];

    char* smemc = smem;
    const int tid = threadIdx.x;
    const int wv  = tid >> 6;
    const int L   = tid & 63;
    const int s   = L & 7;
    const int a   = L >> 3;
    const int b   = blockIdx.x;

    float2* Z = (float2*)smem + wv * 640;            // wave-private FFT buffer
    const float2* R   = (const float2*)(ws + WS_R);
    const float2* win = (const float2*)(ws + WS_WIN);

    // ---- hoist all loop-invariant tables into registers (once per wave) ----
    float2 twA[4], twB[2], twC, twD[4], twE[2], twF, twS[8], winv[5];
    #pragma unroll
    for (int j = 0; j < 4; ++j) twA[j] = R[2 * (L + 64 * j)];
    #pragma unroll
    for (int j = 0; j < 2; ++j) twB[j] = R[4 * (L + 64 * j)];
    twC = R[8 * L];
    #pragma unroll
    for (int j = 0; j < 4; ++j) twD[j] = R[128 * j + 16 * s];
    #pragma unroll
    for (int j = 0; j < 2; ++j) twE[j] = R[256 * j + 32 * s];
    twF = R[64 * s];
    #pragma unroll
    for (int j = 0; j < 8; ++j) twS[j] = R[8 * L + j];   // real-split W_1024^k
    #pragma unroll
    for (int j = 0; j < 5; ++j) winv[j] = win[L + 64 * j];

    for (int c = 0; c < 4; ++c) {
        const int f0 = c * 16 + wv * 4;    // wave's first frame this chunk
        uint4 mgp[4];
        float m512v[4] = {0.0f, 0.0f, 0.0f, 0.0f};

        if (f0 < NFRAME) {                 // wave-uniform guard
            #pragma unroll
            for (int fi = 0; fi < 4; ++fi) {
                const int f = f0 + fi;
                if (f >= NFRAME) continue; // wave-uniform
                const float2* xin = (const float2*)(wave + (size_t)b * NSAMP + (size_t)f * 320);

                float zr[8], zi[8];
                #pragma unroll
                for (int j = 0; j < 8; ++j) { zr[j] = 0.0f; zi[j] = 0.0f; }
                #pragma unroll
                for (int j = 0; j < 5; ++j) {
                    float2 x = xin[L + 64 * j];
                    zr[j] = x.x * winv[j].x;
                    zi[j] = x.y * winv[j].y;
                }

                // ---- register stages on coset n = L + 64j ----
                #pragma unroll
                for (int j = 0; j < 4; ++j) BFLY(j, j + 4, twA[j].x, twA[j].y);
                #pragma unroll
                for (int g = 0; g < 8; g += 4) {
                    #pragma unroll
                    for (int j = 0; j < 2; ++j) BFLY(g + j, g + j + 2, twB[j].x, twB[j].y);
                }
                #pragma unroll
                for (int i0 = 0; i0 < 8; i0 += 2) BFLY(i0, i0 + 1, twC.x, twC.y);

                // ---- exchange 1: write scatter, read contiguous b128 ----
                WAVE_FENCE();
                #pragma unroll
                for (int j = 0; j < 8; ++j)
                    Z[80 * j + 10 * s + a] = make_float2(zr[j], zi[j]);
                WAVE_FENCE();
                {
                    float4 q0 = *(float4*)&Z[10 * L + 0];
                    float4 q1 = *(float4*)&Z[10 * L + 2];
                    float4 q2 = *(float4*)&Z[10 * L + 4];
                    float4 q3 = *(float4*)&Z[10 * L + 6];
                    zr[0] = q0.x; zi[0] = q0.y; zr[1] = q0.z; zi[1] = q0.w;
                    zr[2] = q1.x; zi[2] = q1.y; zr[3] = q1.z; zi[3] = q1.w;
                    zr[4] = q2.x; zi[4] = q2.y; zr[5] = q2.z; zi[5] = q2.w;
                    zr[6] = q3.x; zi[6] = q3.y; zr[7] = q3.z; zi[7] = q3.w;
                }

                // ---- register stages on coset q = 8j + s ----
                #pragma unroll
                for (int j = 0; j < 4; ++j) BFLY(j, j + 4, twD[j].x, twD[j].y);
                #pragma unroll
                for (int g = 0; g < 8; g += 4) {
                    #pragma unroll
                    for (int j = 0; j < 2; ++j) BFLY(g + j, g + j + 2, twE[j].x, twE[j].y);
                }
                #pragma unroll
                for (int i0 = 0; i0 < 8; i0 += 2) BFLY(i0, i0 + 1, twF.x, twF.y);

                // ---- exchange 2 ----
                WAVE_FENCE();
                #pragma unroll
                for (int j = 0; j < 8; ++j)
                    Z[80 * a + 10 * j + s] = make_float2(zr[j], zi[j]);
                WAVE_FENCE();
                {
                    float4 q0 = *(float4*)&Z[10 * L + 0];
                    float4 q1 = *(float4*)&Z[10 * L + 2];
                    float4 q2 = *(float4*)&Z[10 * L + 4];
                    float4 q3 = *(float4*)&Z[10 * L + 6];
                    zr[0] = q0.x; zi[0] = q0.y; zr[1] = q0.z; zi[1] = q0.w;
                    zr[2] = q1.x; zi[2] = q1.y; zr[3] = q1.z; zi[3] = q1.w;
                    zr[4] = q2.x; zi[4] = q2.y; zr[5] = q2.z; zi[5] = q2.w;
                    zr[6] = q3.x; zi[6] = q3.y; zr[7] = q3.z; zi[7] = q3.w;
                }

                // ---- register stages on q = j (size 8,4,2) ----
                {
                    const float C = 0.70710678118654752f;
                    const float w8r[4] = { 1.0f,  C, 0.0f, -C };
                    const float w8i[4] = { 0.0f, -C, -1.0f, -C };
                    #pragma unroll
                    for (int j = 0; j < 4; ++j) BFLY(j, j + 4, w8r[j], w8i[j]);
                    #pragma unroll
                    for (int g = 0; g < 8; g += 4) {
                        BFLY(g + 0, g + 2, 1.0f, 0.0f);
                        BFLY(g + 1, g + 3, 0.0f, -1.0f);
                    }
                    #pragma unroll
                    for (int i0 = 0; i0 < 8; i0 += 2) BFLY(i0, i0 + 1, 1.0f, 0.0f);
                }

                // ---- write X[k] at slot(k), k = rev3(j)*64 + rev6(L) ----
                WAVE_FENCE();
                {
                    const int rev3t[8] = { 0, 4, 2, 6, 1, 5, 3, 7 };
                    int r6 = (int)(__brev((unsigned)L) >> 26);
                    int u  = r6 + 2 * (r6 >> 3);
                    #pragma unroll
                    for (int j = 0; j < 8; ++j)
                        Z[80 * rev3t[j] + u] = make_float2(zr[j], zi[j]);
                }
                WAVE_FENCE();

                // ---- real-split + |X|, k = 8L+j ----
                float Ax[8], Ay[8], Bx[8], By[8];
                {
                    float4 a0 = *(float4*)&Z[10 * L + 0];
                    float4 a1 = *(float4*)&Z[10 * L + 2];
                    float4 a2 = *(float4*)&Z[10 * L + 4];
                    float4 a3 = *(float4*)&Z[10 * L + 6];
                    Ax[0] = a0.x; Ay[0] = a0.y; Ax[1] = a0.z; Ay[1] = a0.w;
                    Ax[2] = a1.x; Ay[2] = a1.y; Ax[3] = a1.z; Ay[3] = a1.w;
                    Ax[4] = a2.x; Ay[4] = a2.y; Ax[5] = a2.z; Ay[5] = a2.w;
                    Ax[6] = a3.x; Ay[6] = a3.y; Ax[7] = a3.z; Ay[7] = a3.w;
                    float4 t0 = *(float4*)&Z[630 - 10 * L + 0];
                    float4 t1 = *(float4*)&Z[630 - 10 * L + 2];
                    float4 t2 = *(float4*)&Z[630 - 10 * L + 4];
                    float4 t3 = *(float4*)&Z[630 - 10 * L + 6];
                    float2 b0 = Z[640 - 10 * L];
                    Bx[0] = b0.x;  By[0] = b0.y;
                    Bx[7] = t0.z;  By[7] = t0.w;
                    Bx[6] = t1.x;  By[6] = t1.y;
                    Bx[5] = t1.z;  By[5] = t1.w;
                    Bx[4] = t2.x;  By[4] = t2.y;
                    Bx[3] = t2.z;  By[3] = t2.w;
                    Bx[2] = t3.x;  By[2] = t3.y;
                    Bx[1] = t3.z;  By[1] = t3.w;
                }
                float mg[8];
                #pragma unroll
                for (int j = 0; j < 8; ++j) {
                    int k = 8 * L + j;
                    if (k == 0) {
                        mg[j]     = fabsf(Ax[0] + Ay[0]);
                        m512v[fi] = fabsf(Ax[0] - Ay[0]);
                    } else {
                        float xer = 0.5f * (Ax[j] + Bx[j]), xei = 0.5f * (Ay[j] - By[j]);
                        float xo  = 0.5f * (Ay[j] + By[j]), xoi = -0.5f * (Ax[j] - Bx[j]);
                        float xr = xer + twS[j].x * xo - twS[j].y * xoi;
                        float xi = xei + twS[j].x * xoi + twS[j].y * xo;
                        mg[j] = sqrtf(xr * xr + xi * xi);
                    }
                }
                mgp[fi].x = pk_f16(mg[0], mg[1]);
                mgp[fi].y = pk_f16(mg[2], mg[3]);
                mgp[fi].z = pk_f16(mg[4], mg[5]);
                mgp[fi].w = pk_f16(mg[6], mg[7]);
                WAVE_FENCE();
            }
        }

        // ---- chunk FFTs done: overlay mag tile [16][552] f16 onto smem ----
        __syncthreads();
        if (f0 < NFRAME) {
            #pragma unroll
            for (int fi = 0; fi < 4; ++fi) {
                if (f0 + fi >= NFRAME) continue;
                const int row = wv * 4 + fi;
                *(uint4*)(smemc + row * 1104 + 16 * L) = mgp[fi];
                if (L < 20) {
                    unsigned v = (L == 0) ? pk_f16(m512v[fi], 0.0f) : 0u;
                    *(unsigned*)(smemc + row * 1104 + 1024 + 4 * L) = v;
                }
            }
        }
        __syncthreads();

        // ---- mel projection: D[16 rows][16 mels] per wave, K = 544 ----
        if (wv < 3) {
            const int nl = L & 15, q = L >> 4;
            const char* ap = smemc + nl * 1104 + q * 16;
            const _Float16* btp = (const _Float16*)(ws + WS_BT)
                                  + (size_t)(wv * 16 + nl) * 544 + q * 8;
            f32x4 acc = {0.0f, 0.0f, 0.0f, 0.0f};
            #pragma unroll
            for (int kk = 0; kk < 17; ++kk) {
                half8 av = *(const half8*)(ap + kk * 64);
                half8 bv = *(const half8*)(btp + kk * 32);
                acc = __builtin_amdgcn_mfma_f32_16x16x32_f16(av, bv, acc, 0, 0, 0);
            }
            const int mel = wv * 16 + nl;
            if (mel < NMEL) {
                #pragma unroll
                for (int r = 0; r < 4; ++r) {
                    int frame = c * 16 + q * 4 + r;     // C/D: row=(lane>>4)*4+r
                    if (frame < NFRAME)
                        lm[frame * NMEL + mel] = (_Float16)__logf(acc[r] + 1e-6f);
                }
            }
        }
        __syncthreads();

        // ---- DCT + scale + lifter, fp32: 208 threads = 16 rows x 13 ceps ----
        if (tid < 16 * NCEP) {
            const int fl = tid / NCEP, cc = tid - fl * NCEP;
            const int frame = c * 16 + fl;
            if (frame < NFRAME) {
                float acc = 0.0f;
                #pragma unroll
                for (int m = 0; m < NMEL; ++m)
                    acc += (float)lm[frame * NMEL + m] * ws[WS_DT + m * 13 + cc];
                cep[frame * NCEP + cc] = acc;
            }
        }
        __syncthreads();   // also protects Z overwrite next chunk
    }

    // ---- deltas in-block: d1 = delta(cep), d2 = delta(d1) ----
    const int TC = NFRAME * NCEP;
    for (int i = tid; i < TC; i += 256) {
        const int t = i / NCEP, cc = i - t * NCEP;
        float acc = 0.0f;
        #pragma unroll
        for (int k = -2; k <= 2; ++k) {
            if (k == 0) continue;
            int tt = t + k;
            tt = tt < 0 ? 0 : (tt > NFRAME - 1 ? NFRAME - 1 : tt);
            acc += (float)k * cep[tt * NCEP + cc];
        }
        d1b[i] = acc * 0.1f;
    }
    __syncthreads();
    for (int i = tid; i < TC; i += 256) {
        const int t = i / NCEP, cc = i - t * NCEP;
        float acc = 0.0f;
        #pragma unroll
        for (int k = -2; k <= 2; ++k) {
            if (k == 0) continue;
            int tt = t + k;
            tt = tt < 0 ? 0 : (tt > NFRAME - 1 ? NFRAME - 1 : tt);
            acc += (float)k * d1b[tt * NCEP + cc];
        }
        const size_t base = ((size_t)b * NFRAME + t) * (3 * NCEP);
        out[base +            cc] = cep[i];
        out[base +     NCEP + cc] = d1b[i];
        out[base + 2 * NCEP + cc] = acc * 0.1f;
    }
}

extern "C" void kernel_launch(void* const* d_in, const int* in_sizes, int n_in,
                              void* d_out, int out_size, void* d_ws, size_t ws_size,
                              hipStream_t stream)
{
    const float* wave   = (const float*)d_in[0];   // [1024][16000] f32
    const float* mel_fb = (const float*)d_in[1];   // [513][40] f32
    float* out = (float*)d_out;                    // [1024][49][39][1] f32
    float* ws  = (float*)d_ws;

    mfcc_prep<<<64, 256, 0, stream>>>(mel_fb, ws);
    mfcc_fused<<<BATCH, 256, 0, stream>>>(wave, ws, out);
}